// Round 1
// baseline (843.257 us; speedup 1.0000x reference)
//
#include <hip/hip_runtime.h>
#include <cstdint>
#include <cstddef>

#define NNODES 50000
#define HD 256
#define NCH 3

typedef __attribute__((ext_vector_type(8))) short shortx8;
typedef __attribute__((ext_vector_type(4))) float floatx4;

__device__ __forceinline__ unsigned short f2bf(float x) {
    union { float f; uint32_t u; } v; v.f = x;
    uint32_t r = v.u + 0x7fffu + ((v.u >> 16) & 1u);   // round-to-nearest-even
    return (unsigned short)(r >> 16);
}

__device__ __forceinline__ float sigf(float x) {
    return 1.0f / (1.0f + __expf(-x));
}
__device__ __forceinline__ float tanhfast(float x) {
    // 1 - 2/(e^{2x}+1): saturates gracefully to +/-1
    return 1.0f - 2.0f / (__expf(2.0f * x) + 1.0f);
}

__device__ __forceinline__ floatx4 mfma16(shortx8 a, shortx8 b, floatx4 c) {
    return __builtin_amdgcn_mfma_f32_16x16x32_bf16(a, b, c, 0, 0, 0);
}

// ---------------------------------------------------------------------------
// Pre-pass: convert weights (fp32, torch [out,in] layout) to bf16 fragments.
// Fragment index fi = ((d*64 + tile)*8 + ks)*64 + lane, 8 bf16 elements each.
// tile 0..15  -> W cols   0..255  = U_f[d][col][k]        (forget gate)
// tile 16..63 -> W cols 256..1023 = U_iou[d][col-256][k]  (i|o|u stacked)
// element e of lane: k = ks*32 + (lane>>4)*8 + e, col = tile*16 + (lane&15)
// ---------------------------------------------------------------------------
__global__ void prep_weights(const float* __restrict__ U_f,
                             const float* __restrict__ U_iou,
                             unsigned short* __restrict__ wsB) {
    int idx = blockIdx.x * 256 + threadIdx.x;     // 98304 frags total
    int lane = idx & 63;
    int ks   = (idx >> 6) & 7;
    int tile = (idx >> 9) & 63;
    int d    = idx >> 15;
    if (d >= NCH) return;
    int col = tile * 16 + (lane & 15);
    int k0  = ks * 32 + (lane >> 4) * 8;
    const float* src = (col < 256)
        ? (U_f   + (((size_t)d * 256 + col)         * 256 + k0))
        : (U_iou + (((size_t)d * 768 + (col - 256)) * 256 + k0));
    shortx8 o;
    #pragma unroll
    for (int e = 0; e < 8; ++e) o[e] = (short)f2bf(src[e]);
    reinterpret_cast<shortx8*>(wsB)[idx] = o;
}

// ---------------------------------------------------------------------------
// Main fused kernel. BM=64 nodes/block, 8 waves = 2 rowgroups x 4 colgroups.
// Each wave: 2 row-tiles (16 nodes each) x 64 elementwise cols
//            (= 4 F col-tiles + 12 IOU col-tiles).
// ---------------------------------------------------------------------------
__global__ __launch_bounds__(512, 2) void treelstm_main(
    const float* __restrict__ nh,       // [N][3][256]
    const float* __restrict__ ncc,      // [N][3][256]
    const float* __restrict__ f_in,     // [N][256]
    const float* __restrict__ iou_in,   // [N][768]
    const unsigned short* __restrict__ wsB,
    float* __restrict__ out)            // h [N][256] then c [N][256]
{
    __shared__ unsigned short lds[32 * 64 * 8];   // [slot][node][8] bf16, 32 KiB

    const int tid  = threadIdx.x;
    const int nb   = blockIdx.x * 64;
    const int lane = tid & 63;
    const int w    = tid >> 6;
    const int rg   = w >> 2;          // rowgroup 0..1  (32 nodes each)
    const int cg   = w & 3;           // colgroup 0..3  (64 elem cols each)
    const int cl   = lane & 15;
    const int g    = lane >> 4;

    const shortx8* Bfr = reinterpret_cast<const shortx8*>(wsB);

    floatx4 accIOU[2][12];            // [row-tile][s*4+j], persistent over children
    floatx4 cagg[2][4];               // c_aggr
    #pragma unroll
    for (int a = 0; a < 2; ++a) {
        #pragma unroll
        for (int b = 0; b < 12; ++b)
            #pragma unroll
            for (int e = 0; e < 4; ++e) accIOU[a][b][e] = 0.0f;
        #pragma unroll
        for (int b = 0; b < 4; ++b)
            #pragma unroll
            for (int e = 0; e < 4; ++e) cagg[a][b][e] = 0.0f;
    }

    for (int d = 0; d < NCH; ++d) {
        __syncthreads();
        // ---- stage nh tile (64 nodes x 256) fp32 -> bf16 LDS ----
        #pragma unroll
        for (int i = 0; i < 4; ++i) {
            int c    = i * 512 + tid;
            int node = c >> 5;
            int slot = c & 31;
            int gn   = nb + node;
            shortx8 o;
            if (gn < NNODES) {
                const float4* q = reinterpret_cast<const float4*>(
                    nh + ((size_t)gn * (NCH * HD) + d * HD + slot * 8));
                float4 u0 = q[0], u1 = q[1];
                o[0] = (short)f2bf(u0.x); o[1] = (short)f2bf(u0.y);
                o[2] = (short)f2bf(u0.z); o[3] = (short)f2bf(u0.w);
                o[4] = (short)f2bf(u1.x); o[5] = (short)f2bf(u1.y);
                o[6] = (short)f2bf(u1.z); o[7] = (short)f2bf(u1.w);
            } else {
                #pragma unroll
                for (int e = 0; e < 8; ++e) o[e] = 0;
            }
            *reinterpret_cast<shortx8*>(&lds[(slot * 64 + node) * 8]) = o;
        }
        __syncthreads();

        // ---- F phase: per-child forget-gate GEMM ----
        floatx4 accF[2][4];
        #pragma unroll
        for (int rt = 0; rt < 2; ++rt)
            #pragma unroll
            for (int j = 0; j < 4; ++j)
                #pragma unroll
                for (int e = 0; e < 4; ++e) accF[rt][j][e] = 0.0f;

        #pragma unroll 2
        for (int ks = 0; ks < 8; ++ks) {
            int an = (ks * 4 + g) * 64 + rg * 32 + cl;
            shortx8 a0 = *reinterpret_cast<const shortx8*>(&lds[an * 8]);
            shortx8 a1 = *reinterpret_cast<const shortx8*>(&lds[(an + 16) * 8]);
            #pragma unroll
            for (int j = 0; j < 4; ++j) {
                int tile = cg * 4 + j;
                shortx8 b = Bfr[((d * 64 + tile) * 8 + ks) * 64 + lane];
                accF[0][j] = mfma16(a0, b, accF[0][j]);
                accF[1][j] = mfma16(a1, b, accF[1][j]);
            }
        }
        // fold: c_aggr += sigmoid(F + f_input) * nc
        #pragma unroll
        for (int rt = 0; rt < 2; ++rt)
            #pragma unroll
            for (int j = 0; j < 4; ++j)
                #pragma unroll
                for (int r = 0; r < 4; ++r) {
                    int n = nb + rg * 32 + rt * 16 + g * 4 + r;
                    if (n < NNODES) {
                        int k = cg * 64 + j * 16 + cl;
                        float fl = accF[rt][j][r] + f_in[(size_t)n * HD + k];
                        cagg[rt][j][r] += sigf(fl) *
                            ncc[(size_t)n * (NCH * HD) + d * HD + k];
                    }
                }

        // ---- IOU phase: accumulated over children ----
        #pragma unroll 2
        for (int ks = 0; ks < 8; ++ks) {
            int an = (ks * 4 + g) * 64 + rg * 32 + cl;
            shortx8 a0 = *reinterpret_cast<const shortx8*>(&lds[an * 8]);
            shortx8 a1 = *reinterpret_cast<const shortx8*>(&lds[(an + 16) * 8]);
            #pragma unroll
            for (int s = 0; s < 3; ++s)
                #pragma unroll
                for (int j = 0; j < 4; ++j) {
                    int tile = 16 + s * 16 + cg * 4 + j;
                    shortx8 b = Bfr[((d * 64 + tile) * 8 + ks) * 64 + lane];
                    accIOU[0][s * 4 + j] = mfma16(a0, b, accIOU[0][s * 4 + j]);
                    accIOU[1][s * 4 + j] = mfma16(a1, b, accIOU[1][s * 4 + j]);
                }
        }
    }

    // ---- epilogue: gates + outputs (iou_input counted twice, as in ref) ----
    #pragma unroll
    for (int rt = 0; rt < 2; ++rt)
        #pragma unroll
        for (int j = 0; j < 4; ++j)
            #pragma unroll
            for (int r = 0; r < 4; ++r) {
                int n = nb + rg * 32 + rt * 16 + g * 4 + r;
                if (n >= NNODES) continue;
                int k = cg * 64 + j * 16 + cl;
                size_t ib = (size_t)n * 768;
                float iv = accIOU[rt][0 + j][r] + 2.0f * iou_in[ib + k];
                float ov = accIOU[rt][4 + j][r] + 2.0f * iou_in[ib + 256 + k];
                float uv = accIOU[rt][8 + j][r] + 2.0f * iou_in[ib + 512 + k];
                float cc = sigf(iv) * tanhfast(uv) + cagg[rt][j][r];
                float hh = sigf(ov) * tanhfast(cc);
                out[(size_t)n * HD + k] = hh;
                out[(size_t)(NNODES + n) * HD + k] = cc;
            }
}

extern "C" void kernel_launch(void* const* d_in, const int* in_sizes, int n_in,
                              void* d_out, int out_size, void* d_ws, size_t ws_size,
                              hipStream_t stream) {
    const float* nh     = (const float*)d_in[0];
    const float* ncc    = (const float*)d_in[1];
    const float* f_in   = (const float*)d_in[2];
    const float* iou_in = (const float*)d_in[3];
    const float* U_f    = (const float*)d_in[4];
    const float* U_iou  = (const float*)d_in[5];
    unsigned short* wsB = (unsigned short*)d_ws;

    // need 3*64*8*64 fragments * 16B = 1.5 MiB of scratch
    if (ws_size < (size_t)(3 * 64 * 8 * 64) * 16) return;

    hipLaunchKernelGGL(prep_weights, dim3(384), dim3(256), 0, stream,
                       U_f, U_iou, wsB);
    hipLaunchKernelGGL(treelstm_main, dim3((NNODES + 63) / 64), dim3(512), 0,
                       stream, nh, ncc, f_in, iou_in, wsB, (float*)d_out);
}

// Round 2
// 323.472 us; speedup vs baseline: 2.6069x; 2.6069x over previous
//
#include <hip/hip_runtime.h>
#include <cstdint>
#include <cstddef>

#define NNODES 50000
#define HD 256
#define NCH 3

typedef __attribute__((ext_vector_type(8))) short shortx8;
typedef __attribute__((ext_vector_type(4))) float floatx4;

__device__ __forceinline__ unsigned short f2bf(float x) {
    union { float f; uint32_t u; } v; v.f = x;
    uint32_t r = v.u + 0x7fffu + ((v.u >> 16) & 1u);   // round-to-nearest-even
    return (unsigned short)(r >> 16);
}

__device__ __forceinline__ float sigf(float x) {
    return 1.0f / (1.0f + __expf(-x));
}
__device__ __forceinline__ float tanhfast(float x) {
    return 1.0f - 2.0f / (__expf(2.0f * x) + 1.0f);
}

__device__ __forceinline__ floatx4 mfma16(shortx8 a, shortx8 b, floatx4 c) {
    return __builtin_amdgcn_mfma_f32_16x16x32_bf16(a, b, c, 0, 0, 0);
}

// ---------------------------------------------------------------------------
// Pre-pass: convert weights (fp32, torch [out,in] layout) to bf16 fragments.
// Fragment index fi = ((d*64 + tile)*8 + ks)*64 + lane, 8 bf16 elements each.
// tile 0..15  -> W cols   0..255  = U_f[d][col][k]        (forget gate)
// tile 16..63 -> W cols 256..1023 = U_iou[d][col-256][k]  (i|o|u stacked)
// element e of lane: k = ks*32 + (lane>>4)*8 + e, col = tile*16 + (lane&15)
// ---------------------------------------------------------------------------
__global__ void prep_weights(const float* __restrict__ U_f,
                             const float* __restrict__ U_iou,
                             unsigned short* __restrict__ wsB) {
    int idx = blockIdx.x * 256 + threadIdx.x;     // 98304 frags total
    int lane = idx & 63;
    int ks   = (idx >> 6) & 7;
    int tile = (idx >> 9) & 63;
    int d    = idx >> 15;
    if (d >= NCH) return;
    int col = tile * 16 + (lane & 15);
    int k0  = ks * 32 + (lane >> 4) * 8;
    const float* src = (col < 256)
        ? (U_f   + (((size_t)d * 256 + col)         * 256 + k0))
        : (U_iou + (((size_t)d * 768 + (col - 256)) * 256 + k0));
    shortx8 o;
    #pragma unroll
    for (int e = 0; e < 8; ++e) o[e] = (short)f2bf(src[e]);
    reinterpret_cast<shortx8*>(wsB)[idx] = o;
}

// ---------------------------------------------------------------------------
// Main fused kernel. 1024 threads = 16 waves, BM = 64 nodes per block.
// Wave w owns ALL 64 nodes x 16 elem-cols [w*16, w*16+16): GEMM tiles
// {F: w, I: 16+w, O: 32+w, U: 48+w}, 4 row-tiles each -> max B-reuse,
// 64 persistent floats/thread (12 IOU floatx4 + 4 cagg float4).
// Elementwise phases run in LINEAR layout via LDS round-trip so all
// global traffic is coalesced float4.
// ---------------------------------------------------------------------------
__global__ __launch_bounds__(1024) void treelstm_main(
    const float* __restrict__ nh,       // [N][3][256]
    const float* __restrict__ ncc,      // [N][3][256]
    const float* __restrict__ f_in,     // [N][256]
    const float* __restrict__ iou_in,   // [N][768]
    const unsigned short* __restrict__ wsB,
    float* __restrict__ out)            // h [N][256] then c [N][256]
{
    extern __shared__ char smem[];
    unsigned short* sA = (unsigned short*)smem;          // 32 KiB bf16 nh tile
    float*          sF = (float*)(smem + 32768);         // 64 KiB fp32 relayout

    const int tid  = threadIdx.x;
    const int nb   = blockIdx.x * 64;
    const int lane = tid & 63;
    const int w    = tid >> 6;        // colgroup 0..15
    const int cl   = lane & 15;
    const int g    = lane >> 4;

    const shortx8* Bfr = reinterpret_cast<const shortx8*>(wsB);

    // linear elementwise mapping: iter i handles 4 floats at
    // e = (i*1024+tid)*4 : node = e>>8, k = e&255  (same across children)
    float4 fin_r[4];                  // f_input, loaded once (child 0)
    float4 cagg[4];
    floatx4 accIOU[4][3];             // [row-tile][gate i/o/u], persistent
    #pragma unroll
    for (int i = 0; i < 4; ++i) cagg[i] = float4{0.f, 0.f, 0.f, 0.f};
    #pragma unroll
    for (int rt = 0; rt < 4; ++rt)
        #pragma unroll
        for (int s = 0; s < 3; ++s)
            #pragma unroll
            for (int e = 0; e < 4; ++e) accIOU[rt][s][e] = 0.0f;

    for (int d = 0; d < NCH; ++d) {
        __syncthreads();
        // ---- stage nh tile (64 nodes x 256) fp32 -> bf16 LDS, coalesced ----
        #pragma unroll
        for (int i = 0; i < 2; ++i) {
            int c    = i * 1024 + tid;
            int node = c >> 5;
            int slot = c & 31;
            int gn   = nb + node;
            shortx8 o;
            if (gn < NNODES) {
                const float4* q = reinterpret_cast<const float4*>(
                    nh + ((size_t)gn * (NCH * HD) + d * HD + slot * 8));
                float4 u0 = q[0], u1 = q[1];
                o[0] = (short)f2bf(u0.x); o[1] = (short)f2bf(u0.y);
                o[2] = (short)f2bf(u0.z); o[3] = (short)f2bf(u0.w);
                o[4] = (short)f2bf(u1.x); o[5] = (short)f2bf(u1.y);
                o[6] = (short)f2bf(u1.z); o[7] = (short)f2bf(u1.w);
            } else {
                #pragma unroll
                for (int e = 0; e < 8; ++e) o[e] = 0;
            }
            *reinterpret_cast<shortx8*>(&sA[(slot * 64 + node) * 8]) = o;
        }
        __syncthreads();

        // ---- GEMM: 4 row-tiles x 4 col-tiles (F,I,O,U), K=256 ----
        floatx4 accF[4];
        #pragma unroll
        for (int rt = 0; rt < 4; ++rt)
            #pragma unroll
            for (int e = 0; e < 4; ++e) accF[rt][e] = 0.0f;

        #pragma unroll 2
        for (int ks = 0; ks < 8; ++ks) {
            int an = (ks * 4 + g) * 64 + cl;
            shortx8 a0 = *reinterpret_cast<const shortx8*>(&sA[an * 8]);
            shortx8 a1 = *reinterpret_cast<const shortx8*>(&sA[(an + 16) * 8]);
            shortx8 a2 = *reinterpret_cast<const shortx8*>(&sA[(an + 32) * 8]);
            shortx8 a3 = *reinterpret_cast<const shortx8*>(&sA[(an + 48) * 8]);
            shortx8 bF = Bfr[((d * 64 +      w) * 8 + ks) * 64 + lane];
            shortx8 bI = Bfr[((d * 64 + 16 + w) * 8 + ks) * 64 + lane];
            shortx8 bO = Bfr[((d * 64 + 32 + w) * 8 + ks) * 64 + lane];
            shortx8 bU = Bfr[((d * 64 + 48 + w) * 8 + ks) * 64 + lane];
            accF[0] = mfma16(a0, bF, accF[0]);
            accF[1] = mfma16(a1, bF, accF[1]);
            accF[2] = mfma16(a2, bF, accF[2]);
            accF[3] = mfma16(a3, bF, accF[3]);
            accIOU[0][0] = mfma16(a0, bI, accIOU[0][0]);
            accIOU[1][0] = mfma16(a1, bI, accIOU[1][0]);
            accIOU[2][0] = mfma16(a2, bI, accIOU[2][0]);
            accIOU[3][0] = mfma16(a3, bI, accIOU[3][0]);
            accIOU[0][1] = mfma16(a0, bO, accIOU[0][1]);
            accIOU[1][1] = mfma16(a1, bO, accIOU[1][1]);
            accIOU[2][1] = mfma16(a2, bO, accIOU[2][1]);
            accIOU[3][1] = mfma16(a3, bO, accIOU[3][1]);
            accIOU[0][2] = mfma16(a0, bU, accIOU[0][2]);
            accIOU[1][2] = mfma16(a1, bU, accIOU[1][2]);
            accIOU[2][2] = mfma16(a2, bU, accIOU[2][2]);
            accIOU[3][2] = mfma16(a3, bU, accIOU[3][2]);
        }

        // ---- relayout F logits (C-layout regs -> [node][k] fp32 LDS) ----
        #pragma unroll
        for (int rt = 0; rt < 4; ++rt)
            #pragma unroll
            for (int r = 0; r < 4; ++r)
                sF[(rt * 16 + g * 4 + r) * 256 + w * 16 + cl] = accF[rt][r];
        __syncthreads();

        // ---- fold: cagg += sigmoid(F + f_in) * nc, linear float4 ----
        #pragma unroll
        for (int i = 0; i < 4; ++i) {
            int e    = (i * 1024 + tid) * 4;
            int node = e >> 8;
            int k    = e & 255;
            int gn   = nb + node;
            if (gn < NNODES) {
                float4 Fv = *reinterpret_cast<float4*>(&sF[node * 256 + k]);
                if (d == 0)
                    fin_r[i] = *reinterpret_cast<const float4*>(
                        f_in + (size_t)gn * HD + k);
                float4 nc = *reinterpret_cast<const float4*>(
                    ncc + (size_t)gn * (NCH * HD) + d * HD + k);
                cagg[i].x += sigf(Fv.x + fin_r[i].x) * nc.x;
                cagg[i].y += sigf(Fv.y + fin_r[i].y) * nc.y;
                cagg[i].z += sigf(Fv.z + fin_r[i].z) * nc.z;
                cagg[i].w += sigf(Fv.w + fin_r[i].w) * nc.w;
            }
        }
    }

    // ---- epilogue: 3 gate passes (i, u, o) through the LDS buffer ----
    float4 ii[4], cc2[4];

    // pass I (gate index 0)
    __syncthreads();
    #pragma unroll
    for (int rt = 0; rt < 4; ++rt)
        #pragma unroll
        for (int r = 0; r < 4; ++r)
            sF[(rt * 16 + g * 4 + r) * 256 + w * 16 + cl] = accIOU[rt][0][r];
    __syncthreads();
    #pragma unroll
    for (int i = 0; i < 4; ++i) {
        int e = (i * 1024 + tid) * 4, node = e >> 8, k = e & 255;
        int gn = nb + node;
        if (gn < NNODES) {
            float4 v  = *reinterpret_cast<float4*>(&sF[node * 256 + k]);
            float4 io = *reinterpret_cast<const float4*>(
                iou_in + (size_t)gn * 768 + k);
            ii[i].x = v.x + 2.0f * io.x; ii[i].y = v.y + 2.0f * io.y;
            ii[i].z = v.z + 2.0f * io.z; ii[i].w = v.w + 2.0f * io.w;
        }
    }

    // pass U (gate index 2): c = sig(i)*tanh(u) + cagg
    __syncthreads();
    #pragma unroll
    for (int rt = 0; rt < 4; ++rt)
        #pragma unroll
        for (int r = 0; r < 4; ++r)
            sF[(rt * 16 + g * 4 + r) * 256 + w * 16 + cl] = accIOU[rt][2][r];
    __syncthreads();
    #pragma unroll
    for (int i = 0; i < 4; ++i) {
        int e = (i * 1024 + tid) * 4, node = e >> 8, k = e & 255;
        int gn = nb + node;
        if (gn < NNODES) {
            float4 v  = *reinterpret_cast<float4*>(&sF[node * 256 + k]);
            float4 io = *reinterpret_cast<const float4*>(
                iou_in + (size_t)gn * 768 + 512 + k);
            cc2[i].x = sigf(ii[i].x) * tanhfast(v.x + 2.0f * io.x) + cagg[i].x;
            cc2[i].y = sigf(ii[i].y) * tanhfast(v.y + 2.0f * io.y) + cagg[i].y;
            cc2[i].z = sigf(ii[i].z) * tanhfast(v.z + 2.0f * io.z) + cagg[i].z;
            cc2[i].w = sigf(ii[i].w) * tanhfast(v.w + 2.0f * io.w) + cagg[i].w;
        }
    }

    // pass O (gate index 1): h = sig(o)*tanh(c); store h and c
    __syncthreads();
    #pragma unroll
    for (int rt = 0; rt < 4; ++rt)
        #pragma unroll
        for (int r = 0; r < 4; ++r)
            sF[(rt * 16 + g * 4 + r) * 256 + w * 16 + cl] = accIOU[rt][1][r];
    __syncthreads();
    #pragma unroll
    for (int i = 0; i < 4; ++i) {
        int e = (i * 1024 + tid) * 4, node = e >> 8, k = e & 255;
        int gn = nb + node;
        if (gn < NNODES) {
            float4 v  = *reinterpret_cast<float4*>(&sF[node * 256 + k]);
            float4 io = *reinterpret_cast<const float4*>(
                iou_in + (size_t)gn * 768 + 256 + k);
            float4 hh;
            hh.x = sigf(v.x + 2.0f * io.x) * tanhfast(cc2[i].x);
            hh.y = sigf(v.y + 2.0f * io.y) * tanhfast(cc2[i].y);
            hh.z = sigf(v.z + 2.0f * io.z) * tanhfast(cc2[i].z);
            hh.w = sigf(v.w + 2.0f * io.w) * tanhfast(cc2[i].w);
            *reinterpret_cast<float4*>(out + (size_t)gn * HD + k) = hh;
            *reinterpret_cast<float4*>(out + (size_t)(NNODES + gn) * HD + k) = cc2[i];
        }
    }
}

extern "C" void kernel_launch(void* const* d_in, const int* in_sizes, int n_in,
                              void* d_out, int out_size, void* d_ws, size_t ws_size,
                              hipStream_t stream) {
    const float* nh     = (const float*)d_in[0];
    const float* ncc    = (const float*)d_in[1];
    const float* f_in   = (const float*)d_in[2];
    const float* iou_in = (const float*)d_in[3];
    const float* U_f    = (const float*)d_in[4];
    const float* U_iou  = (const float*)d_in[5];
    unsigned short* wsB = (unsigned short*)d_ws;

    if (ws_size < (size_t)(3 * 64 * 8 * 64) * 16) return;

    hipLaunchKernelGGL(prep_weights, dim3(384), dim3(256), 0, stream,
                       U_f, U_iou, wsB);
    hipLaunchKernelGGL(treelstm_main, dim3((NNODES + 63) / 64), dim3(1024),
                       98304, stream, nh, ncc, f_in, iou_in, wsB, (float*)d_out);
}

// Round 3
// 307.192 us; speedup vs baseline: 2.7451x; 1.0530x over previous
//
#include <hip/hip_runtime.h>
#include <cstdint>
#include <cstddef>

#define NNODES 50000
#define HD 256
#define NCH 3
#define BM 32

typedef __attribute__((ext_vector_type(8))) short shortx8;
typedef __attribute__((ext_vector_type(4))) float floatx4;

__device__ __forceinline__ unsigned short f2bf(float x) {
    union { float f; uint32_t u; } v; v.f = x;
    uint32_t r = v.u + 0x7fffu + ((v.u >> 16) & 1u);   // round-to-nearest-even
    return (unsigned short)(r >> 16);
}
__device__ __forceinline__ float bf2f(unsigned short u) {
    union { uint32_t u; float f; } v; v.u = ((uint32_t)u) << 16; return v.f;
}
__device__ __forceinline__ float sigf(float x) {
    return 1.0f / (1.0f + __expf(-x));
}
__device__ __forceinline__ float tanhfast(float x) {
    return 1.0f - 2.0f / (__expf(2.0f * x) + 1.0f);
}
__device__ __forceinline__ floatx4 mfma16(shortx8 a, shortx8 b, floatx4 c) {
    return __builtin_amdgcn_mfma_f32_16x16x32_bf16(a, b, c, 0, 0, 0);
}

// ---------------------------------------------------------------------------
// Pre-pass: weights fp32 [out,in] -> bf16 MFMA B-fragments in d_ws.
// fi = ((d*64 + tile)*8 + ks)*64 + lane ; 8 bf16 each.
// tile 0..15 -> U_f cols; 16..31 -> I; 32..47 -> O; 48..63 -> U.
// elem e: k = ks*32 + (lane>>4)*8 + e, col = tile*16 + (lane&15)
// ---------------------------------------------------------------------------
__global__ void prep_weights(const float* __restrict__ U_f,
                             const float* __restrict__ U_iou,
                             unsigned short* __restrict__ wsB) {
    int idx = blockIdx.x * 256 + threadIdx.x;
    int lane = idx & 63;
    int ks   = (idx >> 6) & 7;
    int tile = (idx >> 9) & 63;
    int d    = idx >> 15;
    if (d >= NCH) return;
    int col = tile * 16 + (lane & 15);
    int k0  = ks * 32 + (lane >> 4) * 8;
    const float* src = (col < 256)
        ? (U_f   + (((size_t)d * 256 + col)         * 256 + k0))
        : (U_iou + (((size_t)d * 768 + (col - 256)) * 256 + k0));
    shortx8 o;
    #pragma unroll
    for (int e = 0; e < 8; ++e) o[e] = (short)f2bf(src[e]);
    reinterpret_cast<shortx8*>(wsB)[idx] = o;
}

// ---------------------------------------------------------------------------
// Main kernel: 512 threads (8 waves), BM=32 nodes, 64 KiB LDS -> 2 blocks/CU.
// Wave w owns elem cols [w*32, w*32+32): F tiles {2w,2w+1}, I {16+..},
// O {32+..}, U {48+..}; 2 row-tiles. F phase per child (transient acc),
// then one K=768 IOU GEMM (48 persistent acc), epilogue in 3 passes via
// 16 KiB bf16 relayout buffer. All global traffic coalesced float4.
// ---------------------------------------------------------------------------
__global__ __launch_bounds__(512, 4) void treelstm_main(
    const float* __restrict__ nh,       // [N][3][256]
    const float* __restrict__ ncc,      // [N][3][256]
    const float* __restrict__ f_in,     // [N][256]
    const float* __restrict__ iou_in,   // [N][768]
    const unsigned short* __restrict__ wsB,
    float* __restrict__ out)            // h [N][256] then c [N][256]
{
    __shared__ unsigned short sA[NCH * 32 * BM * 8];  // 48 KiB [d][slot][node][8]
    __shared__ unsigned short sF[BM * 256];           // 16 KiB bf16 relayout

    const int tid  = threadIdx.x;
    const int nb   = blockIdx.x * BM;
    const int lane = tid & 63;
    const int w    = tid >> 6;        // 0..7
    const int cl   = lane & 15;
    const int g    = lane >> 4;

    const shortx8* Bfr = reinterpret_cast<const shortx8*>(wsB);

    // ---- stage nh for ALL children, fp32 -> bf16, coalesced ----
    #pragma unroll
    for (int i = 0; i < 6; ++i) {
        int c    = i * 512 + tid;          // 0..3071
        int d    = c >> 10;
        int node = (c >> 5) & 31;
        int slot = c & 31;
        int gn   = nb + node;
        shortx8 o;
        if (gn < NNODES) {
            const float4* q = reinterpret_cast<const float4*>(
                nh + ((size_t)gn * (NCH * HD) + d * HD + slot * 8));
            float4 u0 = q[0], u1 = q[1];
            o[0] = (short)f2bf(u0.x); o[1] = (short)f2bf(u0.y);
            o[2] = (short)f2bf(u0.z); o[3] = (short)f2bf(u0.w);
            o[4] = (short)f2bf(u1.x); o[5] = (short)f2bf(u1.y);
            o[6] = (short)f2bf(u1.z); o[7] = (short)f2bf(u1.w);
        } else {
            #pragma unroll
            for (int e = 0; e < 8; ++e) o[e] = 0;
        }
        *reinterpret_cast<shortx8*>(&sA[((d * 32 + slot) * BM + node) * 8]) = o;
    }
    __syncthreads();

    // linear elementwise mapping: iter i -> e=(i*512+tid)*4, node=e>>8, k=e&255
    float4 fin_r[4];
    float4 cagg[4];
    #pragma unroll
    for (int i = 0; i < 4; ++i) cagg[i] = float4{0.f, 0.f, 0.f, 0.f};

    // ================= F phase: per-child forget gate =================
    for (int d = 0; d < NCH; ++d) {
        // prefetch ncc (and f_in once) -- hides under the F-GEMM below
        float4 ncr[4];
        #pragma unroll
        for (int i = 0; i < 4; ++i) {
            int e = (i * 512 + tid) * 4, node = e >> 8, k = e & 255;
            int gn = nb + node;
            if (gn < NNODES) {
                ncr[i] = *reinterpret_cast<const float4*>(
                    ncc + (size_t)gn * (NCH * HD) + d * HD + k);
                if (d == 0)
                    fin_r[i] = *reinterpret_cast<const float4*>(
                        f_in + (size_t)gn * HD + k);
            }
        }

        floatx4 accF[2][2];
        #pragma unroll
        for (int rt = 0; rt < 2; ++rt)
            #pragma unroll
            for (int j = 0; j < 2; ++j)
                #pragma unroll
                for (int e = 0; e < 4; ++e) accF[rt][j][e] = 0.0f;

        #pragma unroll
        for (int ks = 0; ks < 8; ++ks) {
            int an = (d * 32 + ks * 4 + g) * BM + cl;
            shortx8 a0 = *reinterpret_cast<const shortx8*>(&sA[an * 8]);
            shortx8 a1 = *reinterpret_cast<const shortx8*>(&sA[(an + 16) * 8]);
            shortx8 b0 = Bfr[((d * 64 + 2 * w)     * 8 + ks) * 64 + lane];
            shortx8 b1 = Bfr[((d * 64 + 2 * w + 1) * 8 + ks) * 64 + lane];
            accF[0][0] = mfma16(a0, b0, accF[0][0]);
            accF[1][0] = mfma16(a1, b0, accF[1][0]);
            accF[0][1] = mfma16(a0, b1, accF[0][1]);
            accF[1][1] = mfma16(a1, b1, accF[1][1]);
        }

        __syncthreads();   // prev fold's sF reads complete
        #pragma unroll
        for (int rt = 0; rt < 2; ++rt)
            #pragma unroll
            for (int j = 0; j < 2; ++j)
                #pragma unroll
                for (int r = 0; r < 4; ++r)
                    sF[(rt * 16 + g * 4 + r) * 256 + w * 32 + j * 16 + cl] =
                        f2bf(accF[rt][j][r]);
        __syncthreads();

        // fold: cagg += sigmoid(F + f_in) * nc   (linear layout)
        #pragma unroll
        for (int i = 0; i < 4; ++i) {
            int e = (i * 512 + tid) * 4, node = e >> 8, k = e & 255;
            int gn = nb + node;
            if (gn < NNODES) {
                ushort4 Fb = *reinterpret_cast<ushort4*>(&sF[node * 256 + k]);
                cagg[i].x += sigf(bf2f(Fb.x) + fin_r[i].x) * ncr[i].x;
                cagg[i].y += sigf(bf2f(Fb.y) + fin_r[i].y) * ncr[i].y;
                cagg[i].z += sigf(bf2f(Fb.z) + fin_r[i].z) * ncr[i].z;
                cagg[i].w += sigf(bf2f(Fb.w) + fin_r[i].w) * ncr[i].w;
            }
        }
    }

    // ================= IOU GEMM: K = 768 (children concatenated) ==========
    floatx4 acc[2][6];     // [row-tile][{I0,I1,O0,O1,U0,U1}]
    #pragma unroll
    for (int rt = 0; rt < 2; ++rt)
        #pragma unroll
        for (int q = 0; q < 6; ++q)
            #pragma unroll
            for (int e = 0; e < 4; ++e) acc[rt][q][e] = 0.0f;

    for (int d = 0; d < NCH; ++d) {
        #pragma unroll
        for (int ks = 0; ks < 8; ++ks) {
            int an = (d * 32 + ks * 4 + g) * BM + cl;
            shortx8 a0 = *reinterpret_cast<const shortx8*>(&sA[an * 8]);
            shortx8 a1 = *reinterpret_cast<const shortx8*>(&sA[(an + 16) * 8]);
            #pragma unroll
            for (int q = 0; q < 3; ++q) {         // I, O, U
                shortx8 b0 = Bfr[((d * 64 + 16 + q * 16 + 2 * w)     * 8 + ks) * 64 + lane];
                shortx8 b1 = Bfr[((d * 64 + 16 + q * 16 + 2 * w + 1) * 8 + ks) * 64 + lane];
                acc[0][q * 2 + 0] = mfma16(a0, b0, acc[0][q * 2 + 0]);
                acc[1][q * 2 + 0] = mfma16(a1, b0, acc[1][q * 2 + 0]);
                acc[0][q * 2 + 1] = mfma16(a0, b1, acc[0][q * 2 + 1]);
                acc[1][q * 2 + 1] = mfma16(a1, b1, acc[1][q * 2 + 1]);
            }
        }
    }

    // ================= epilogue: 3 passes (I, U, O) via sF ================
    float4 ii[4], cc2[4], iol[4];

    // ---- pass I (acc slots 0,1; iou_in offset 0) ----
    #pragma unroll
    for (int i = 0; i < 4; ++i) {
        int e = (i * 512 + tid) * 4, node = e >> 8, k = e & 255;
        int gn = nb + node;
        if (gn < NNODES)
            iol[i] = *reinterpret_cast<const float4*>(iou_in + (size_t)gn * 768 + k);
    }
    __syncthreads();
    #pragma unroll
    for (int rt = 0; rt < 2; ++rt)
        #pragma unroll
        for (int j = 0; j < 2; ++j)
            #pragma unroll
            for (int r = 0; r < 4; ++r)
                sF[(rt * 16 + g * 4 + r) * 256 + w * 32 + j * 16 + cl] =
                    f2bf(acc[rt][j][r]);
    __syncthreads();
    #pragma unroll
    for (int i = 0; i < 4; ++i) {
        int e = (i * 512 + tid) * 4, node = e >> 8, k = e & 255;
        int gn = nb + node;
        if (gn < NNODES) {
            ushort4 Vb = *reinterpret_cast<ushort4*>(&sF[node * 256 + k]);
            ii[i].x = bf2f(Vb.x) + 2.0f * iol[i].x;
            ii[i].y = bf2f(Vb.y) + 2.0f * iol[i].y;
            ii[i].z = bf2f(Vb.z) + 2.0f * iol[i].z;
            ii[i].w = bf2f(Vb.w) + 2.0f * iol[i].w;
        }
    }

    // ---- pass U (acc slots 4,5; iou_in offset 512): c = sig(i)*tanh(u)+cagg
    #pragma unroll
    for (int i = 0; i < 4; ++i) {
        int e = (i * 512 + tid) * 4, node = e >> 8, k = e & 255;
        int gn = nb + node;
        if (gn < NNODES)
            iol[i] = *reinterpret_cast<const float4*>(iou_in + (size_t)gn * 768 + 512 + k);
    }
    __syncthreads();
    #pragma unroll
    for (int rt = 0; rt < 2; ++rt)
        #pragma unroll
        for (int j = 0; j < 2; ++j)
            #pragma unroll
            for (int r = 0; r < 4; ++r)
                sF[(rt * 16 + g * 4 + r) * 256 + w * 32 + j * 16 + cl] =
                    f2bf(acc[rt][4 + j][r]);
    __syncthreads();
    #pragma unroll
    for (int i = 0; i < 4; ++i) {
        int e = (i * 512 + tid) * 4, node = e >> 8, k = e & 255;
        int gn = nb + node;
        if (gn < NNODES) {
            ushort4 Vb = *reinterpret_cast<ushort4*>(&sF[node * 256 + k]);
            cc2[i].x = sigf(ii[i].x) * tanhfast(bf2f(Vb.x) + 2.0f * iol[i].x) + cagg[i].x;
            cc2[i].y = sigf(ii[i].y) * tanhfast(bf2f(Vb.y) + 2.0f * iol[i].y) + cagg[i].y;
            cc2[i].z = sigf(ii[i].z) * tanhfast(bf2f(Vb.z) + 2.0f * iol[i].z) + cagg[i].z;
            cc2[i].w = sigf(ii[i].w) * tanhfast(bf2f(Vb.w) + 2.0f * iol[i].w) + cagg[i].w;
        }
    }

    // ---- pass O (acc slots 2,3; iou_in offset 256): h = sig(o)*tanh(c) ----
    #pragma unroll
    for (int i = 0; i < 4; ++i) {
        int e = (i * 512 + tid) * 4, node = e >> 8, k = e & 255;
        int gn = nb + node;
        if (gn < NNODES)
            iol[i] = *reinterpret_cast<const float4*>(iou_in + (size_t)gn * 768 + 256 + k);
    }
    __syncthreads();
    #pragma unroll
    for (int rt = 0; rt < 2; ++rt)
        #pragma unroll
        for (int j = 0; j < 2; ++j)
            #pragma unroll
            for (int r = 0; r < 4; ++r)
                sF[(rt * 16 + g * 4 + r) * 256 + w * 32 + j * 16 + cl] =
                    f2bf(acc[rt][2 + j][r]);
    __syncthreads();
    #pragma unroll
    for (int i = 0; i < 4; ++i) {
        int e = (i * 512 + tid) * 4, node = e >> 8, k = e & 255;
        int gn = nb + node;
        if (gn < NNODES) {
            ushort4 Vb = *reinterpret_cast<ushort4*>(&sF[node * 256 + k]);
            float4 hh;
            hh.x = sigf(bf2f(Vb.x) + 2.0f * iol[i].x) * tanhfast(cc2[i].x);
            hh.y = sigf(bf2f(Vb.y) + 2.0f * iol[i].y) * tanhfast(cc2[i].y);
            hh.z = sigf(bf2f(Vb.z) + 2.0f * iol[i].z) * tanhfast(cc2[i].z);
            hh.w = sigf(bf2f(Vb.w) + 2.0f * iol[i].w) * tanhfast(cc2[i].w);
            *reinterpret_cast<float4*>(out + (size_t)gn * HD + k) = hh;
            *reinterpret_cast<float4*>(out + (size_t)(NNODES + gn) * HD + k) = cc2[i];
        }
    }
}

extern "C" void kernel_launch(void* const* d_in, const int* in_sizes, int n_in,
                              void* d_out, int out_size, void* d_ws, size_t ws_size,
                              hipStream_t stream) {
    const float* nh     = (const float*)d_in[0];
    const float* ncc    = (const float*)d_in[1];
    const float* f_in   = (const float*)d_in[2];
    const float* iou_in = (const float*)d_in[3];
    const float* U_f    = (const float*)d_in[4];
    const float* U_iou  = (const float*)d_in[5];
    unsigned short* wsB = (unsigned short*)d_ws;

    if (ws_size < (size_t)(3 * 64 * 8 * 64) * 16) return;

    hipLaunchKernelGGL(prep_weights, dim3(384), dim3(256), 0, stream,
                       U_f, U_iou, wsB);
    hipLaunchKernelGGL(treelstm_main, dim3((NNODES + BM - 1) / BM), dim3(512),
                       0, stream, nh, ncc, f_in, iou_in, wsB, (float*)d_out);
}